// Round 2
// baseline (551.657 us; speedup 1.0000x reference)
//
#include <hip/hip_runtime.h>
#include <cstdint>

#define P_ 12
#define B_ 32
#define V_ 32
#define F_ 256
#define S_ 32
#define NL_ 16
#define LF_ 64
#define T_ 20
#define H_ 8
#define D_ 32
#define L_ 512

// ---------------------------------------------------------------------------
// Kernel M: precompute masks. Bool inputs arrive as int32 (harness converts
// numpy bool -> int32; "integer -> const int*").
//   mlbits[b*16 + w] bit i  = mask_lanes[l/NL, b, l%NL] where l = w*32+i
//   (position-major flatten quirk of the reference)
//   mi[b*32 + v] = any_t mask_input[t,b,v]
// ---------------------------------------------------------------------------
__global__ __launch_bounds__(256) void masks_kernel(
    const int* __restrict__ mask_input,
    const int* __restrict__ mask_lanes,
    unsigned int* __restrict__ mlbits, int* __restrict__ mi) {
  int t = blockIdx.x * 256 + threadIdx.x;
  if (t < B_ * 16) {                       // 512 words of 32 lane-mask bits
    int b = t >> 4, w = t & 15;
    unsigned int bits = 0u;
    for (int i = 0; i < 32; ++i) {
      int l = w * 32 + i;
      int s = l >> 4;        // l / NL_
      int nl = l & 15;       // l % NL_
      if (mask_lanes[(s * B_ + b) * NL_ + nl]) bits |= (1u << i);
    }
    mlbits[b * 16 + w] = bits;
  } else if (t < B_ * 16 + B_ * V_) {
    int i = t - B_ * 16;
    int b = i >> 5, v = i & 31;
    int any = 0;
    for (int tt = 0; tt < T_; ++tt) any |= mask_input[(tt * B_ + b) * V_ + v];
    mi[i] = any ? 1 : 0;
  }
}

// ---------------------------------------------------------------------------
// Kernel A: K/V projection + log_sigmoid(V).
// 32 lane-rows per block staged in LDS; thread f owns output feature f.
// keyf[(b*L + l)*F + f], lsvf likewise; l = nl*S + s (lane-major flatten).
// ---------------------------------------------------------------------------
__global__ __launch_bounds__(256) void proj_kernel(
    const float* __restrict__ lanes,
    const float* __restrict__ Wk, const float* __restrict__ bk,
    const float* __restrict__ Wv, const float* __restrict__ bv,
    float* __restrict__ keyf, float* __restrict__ lsvf) {
  __shared__ float in[32][64];
  int r0 = blockIdx.x * 32;
  int tid = threadIdx.x;
  for (int t = tid; t < 32 * 64 / 4; t += 256) {
    int rr = t >> 4;
    int i0 = (t & 15) * 4;
    int row = r0 + rr;
    int b = row >> 9, l = row & 511;
    int nl = l >> 5, s = l & 31;
    float4 v = *(const float4*)&lanes[((s * B_ + b) * NL_ + nl) * LF_ + i0];
    *(float4*)&in[rr][i0] = v;
  }
  __syncthreads();
  int f = tid;
  float accK[32], accV[32];
#pragma unroll
  for (int r = 0; r < 32; ++r) { accK[r] = 0.f; accV[r] = 0.f; }
  for (int i = 0; i < 64; ++i) {
    float wk = Wk[i * F_ + f];
    float wv = Wv[i * F_ + f];
#pragma unroll
    for (int r = 0; r < 32; ++r) {
      accK[r] = fmaf(in[r][i], wk, accK[r]);
      accV[r] = fmaf(in[r][i], wv, accV[r]);
    }
  }
  float bkf = bk[f], bvf = bv[f];
#pragma unroll
  for (int r = 0; r < 32; ++r) {
    int row = r0 + r;
    keyf[row * F_ + f] = accK[r] + bkf;
    float x = accV[r] + bvf;
    // stable log_sigmoid
    float ls = fminf(x, 0.f) - log1pf(__expf(-fabsf(x)));
    lsvf[row * F_ + f] = ls;
  }
}

// ---------------------------------------------------------------------------
// Kernel B: attention for one (p,b,h).
// 256 threads: thread (v = tid>>3, g = tid&7) owns scores for l = g*64+k.
// K tile (512x32 fp32 = 64KB LDS) stored XOR-swizzled: elem j at j^((l>>6)<<2)
//   -> 8 g-lanes hit 8 distinct bank-quads; same-g lanes broadcast. Conflict-free.
// Softmax per q-row via width-8 shfl_xor. P stays in registers (64/thread).
// Then LDS reloaded with log_sigmoid(V) tile, PV accumulated, g-lanes reduced.
// ---------------------------------------------------------------------------
__global__ __launch_bounds__(256) void attn_kernel(
    const float* __restrict__ query,
    const float* __restrict__ keyf, const float* __restrict__ lsvf,
    const unsigned int* __restrict__ mlbits, const int* __restrict__ mi,
    float* __restrict__ out0) {
  __shared__ float KV[L_ * D_];  // 64 KB, swizzled
  int pbh = blockIdx.x;
  int h = pbh & 7;
  int b = (pbh >> 3) & 31;
  int p = pbh >> 8;
  int tid = threadIdx.x;
  int v = tid >> 3, g = tid & 7;
  int gx = g << 2;

  // ---- load K tile (swizzled) ----
  for (int t = tid; t < L_ * D_ / 4; t += 256) {
    int l = t >> 3;
    int j0 = (t & 7) * 4;
    float4 kv = *(const float4*)&keyf[(b * L_ + l) * F_ + h * D_ + j0];
    int sw = j0 ^ ((l >> 6) << 2);
    *(float4*)&KV[l * D_ + sw] = kv;
  }

  // per-thread Q row (8 lanes share v -> L1 broadcast)
  float4 q4[8];
  const float* qp = &query[((p * B_ + b) * V_ + v) * F_ + h * D_];
#pragma unroll
  for (int m = 0; m < 8; ++m) q4[m] = *(const float4*)&qp[4 * m];

  int miv = mi[b * V_ + v];
  unsigned int mw0 = mlbits[b * 16 + 2 * g];
  unsigned int mw1 = mlbits[b * 16 + 2 * g + 1];

  __syncthreads();

  // ---- scores ----
  float sc[64];
#pragma unroll 8
  for (int k = 0; k < 64; ++k) {
    int l = (g << 6) + k;
    const float* kp = &KV[l * D_];
    float acc = 0.f;
#pragma unroll
    for (int m = 0; m < 8; ++m) {
      float4 kk = *(const float4*)&kp[(4 * m) ^ gx];
      acc = fmaf(q4[m].x, kk.x, acc);
      acc = fmaf(q4[m].y, kk.y, acc);
      acc = fmaf(q4[m].z, kk.z, acc);
      acc = fmaf(q4[m].w, kk.w, acc);
    }
    unsigned int bit = (k < 32) ? ((mw0 >> k) & 1u) : ((mw1 >> (k - 32)) & 1u);
    sc[k] = (bit && miv) ? acc : -1e9f;
  }

  // ---- softmax over l (row spans 8 consecutive lanes) ----
  float M = -3.4e38f;
#pragma unroll
  for (int k = 0; k < 64; ++k) M = fmaxf(M, sc[k]);
  M = fmaxf(M, __shfl_xor(M, 1));
  M = fmaxf(M, __shfl_xor(M, 2));
  M = fmaxf(M, __shfl_xor(M, 4));
  float sum = 0.f;
#pragma unroll
  for (int k = 0; k < 64; ++k) {
    sc[k] = __expf(sc[k] - M);
    sum += sc[k];
  }
  sum += __shfl_xor(sum, 1);
  sum += __shfl_xor(sum, 2);
  sum += __shfl_xor(sum, 4);
  float inv = 1.f / sum;
#pragma unroll
  for (int k = 0; k < 64; ++k) sc[k] *= inv;

  // ---- reload LDS with log_sigmoid(V) tile ----
  __syncthreads();
  for (int t = tid; t < L_ * D_ / 4; t += 256) {
    int l = t >> 3;
    int j0 = (t & 7) * 4;
    float4 kv = *(const float4*)&lsvf[(b * L_ + l) * F_ + h * D_ + j0];
    int sw = j0 ^ ((l >> 6) << 2);
    *(float4*)&KV[l * D_ + sw] = kv;
  }
  __syncthreads();

  // ---- PV ----
  float acc[32];
#pragma unroll
  for (int j = 0; j < 32; ++j) acc[j] = 0.f;
#pragma unroll 8
  for (int k = 0; k < 64; ++k) {
    int l = (g << 6) + k;
    float pk = sc[k];
    const float* vp = &KV[l * D_];
#pragma unroll
    for (int m = 0; m < 8; ++m) {
      float4 vv = *(const float4*)&vp[(4 * m) ^ gx];
      acc[4 * m + 0] = fmaf(pk, vv.x, acc[4 * m + 0]);
      acc[4 * m + 1] = fmaf(pk, vv.y, acc[4 * m + 1]);
      acc[4 * m + 2] = fmaf(pk, vv.z, acc[4 * m + 2]);
      acc[4 * m + 3] = fmaf(pk, vv.w, acc[4 * m + 3]);
    }
  }
  // reduce partial sums across the 8 g-lanes of this row
#pragma unroll
  for (int j = 0; j < 32; ++j) {
    acc[j] += __shfl_xor(acc[j], 1);
    acc[j] += __shfl_xor(acc[j], 2);
    acc[j] += __shfl_xor(acc[j], 4);
  }
  // lane g writes features [g*4, g*4+4) with exp() applied
  float4 o;
  o.x = __expf(acc[gx + 0]);
  o.y = __expf(acc[gx + 1]);
  o.z = __expf(acc[gx + 2]);
  o.w = __expf(acc[gx + 3]);
  *(float4*)&out0[((p * B_ + b) * V_ + v) * F_ + h * D_ + gx] = o;
}

// ---------------------------------------------------------------------------
// Kernel C: combine = out0 @ Wc + bc, 16 rows per block.
// ---------------------------------------------------------------------------
__global__ __launch_bounds__(256) void combine_kernel(
    const float* __restrict__ out0, const float* __restrict__ Wc,
    const float* __restrict__ bc, float* __restrict__ out) {
  __shared__ float rows[16][256];
  int r0 = blockIdx.x * 16;
  int tid = threadIdx.x;
  for (int t = tid; t < 16 * 256 / 4; t += 256) {
    int rr = t >> 6;
    int i0 = (t & 63) * 4;
    *(float4*)&rows[rr][i0] = *(const float4*)&out0[(r0 + rr) * F_ + i0];
  }
  __syncthreads();
  int f = tid;
  float acc[16];
#pragma unroll
  for (int r = 0; r < 16; ++r) acc[r] = 0.f;
  for (int i = 0; i < 256; ++i) {
    float w = Wc[i * F_ + f];
#pragma unroll
    for (int r = 0; r < 16; ++r) acc[r] = fmaf(rows[r][i], w, acc[r]);
  }
  float bcf = bc[f];
#pragma unroll
  for (int r = 0; r < 16; ++r) out[(r0 + r) * F_ + f] = acc[r] + bcf;
}

// ---------------------------------------------------------------------------
extern "C" void kernel_launch(void* const* d_in, const int* in_sizes, int n_in,
                              void* d_out, int out_size, void* d_ws, size_t ws_size,
                              hipStream_t stream) {
  const float* query = (const float*)d_in[0];
  const float* lanes = (const float*)d_in[1];
  const int* mask_input = (const int*)d_in[2];
  const int* mask_lanes = (const int*)d_in[3];
  const float* Wk = (const float*)d_in[4];
  const float* bk = (const float*)d_in[5];
  const float* Wv = (const float*)d_in[6];
  const float* bv = (const float*)d_in[7];
  const float* Wc = (const float*)d_in[8];
  const float* bc = (const float*)d_in[9];
  float* out = (float*)d_out;

  float* ws = (float*)d_ws;
  float* keyf = ws;                      // B*L*F = 4,194,304 floats
  float* lsvf = ws + 4194304;            // 4,194,304 floats
  float* out0 = ws + 8388608;            // P*B*V*F = 3,145,728 floats
  unsigned int* mlbits = (unsigned int*)(ws + 11534336);  // 512 words
  int* mi = (int*)(mlbits + 512);                          // 1024 ints

  masks_kernel<<<6, 256, 0, stream>>>(mask_input, mask_lanes, mlbits, mi);
  proj_kernel<<<B_ * L_ / 32, 256, 0, stream>>>(lanes, Wk, bk, Wv, bv, keyf, lsvf);
  attn_kernel<<<P_ * B_ * H_, 256, 0, stream>>>(query, keyf, lsvf, mlbits, mi, out0);
  combine_kernel<<<P_ * B_ * V_ / 16, 256, 0, stream>>>(out0, Wc, bc, out);
}

// Round 3
// 114.753 us; speedup vs baseline: 4.8074x; 4.8074x over previous
//
#include <hip/hip_runtime.h>
#include <cstdint>

#define P_ 12
#define B_ 32
#define V_ 32
#define F_ 256
#define S_ 32
#define NL_ 16
#define LF_ 64
#define T_ 20
#define H_ 8
#define D_ 32
#define L_ 512

typedef short bf16x8 __attribute__((ext_vector_type(8)));
typedef float f32x4 __attribute__((ext_vector_type(4)));

static __device__ __forceinline__ short f2bf(float f) {
  uint32_t u = __builtin_bit_cast(uint32_t, f);
  uint32_t r = u + 0x7FFFu + ((u >> 16) & 1u);  // RNE
  return (short)(r >> 16);
}

// ---------------------------------------------------------------------------
// Kernel M: mask precompute.
//  maskr[b*16 + r] bit lt = mask_lanes[lt, b, r]   (mask for l = lt*16 + r,
//    since reference mask index l -> s = l>>4 = lt, nl = l&15 = r)
//  mi[b*32 + v] = any_t mask_input[t,b,v]
// ---------------------------------------------------------------------------
__global__ __launch_bounds__(256) void masks_kernel(
    const int* __restrict__ mask_input, const int* __restrict__ mask_lanes,
    unsigned int* __restrict__ maskr, int* __restrict__ mi) {
  int t = blockIdx.x * 256 + threadIdx.x;
  if (t < B_ * 16) {
    int b = t >> 4, r = t & 15;
    unsigned int bits = 0u;
    for (int lt = 0; lt < 32; ++lt)
      if (mask_lanes[(lt * B_ + b) * NL_ + r]) bits |= (1u << lt);
    maskr[t] = bits;
  } else if (t < B_ * 16 + B_ * V_) {
    int i = t - B_ * 16;
    int b = i >> 5, v = i & 31;
    int any = 0;
    for (int tt = 0; tt < T_; ++tt) any |= mask_input[(tt * B_ + b) * V_ + v];
    mi[i] = any ? 1 : 0;
  }
}

// ---------------------------------------------------------------------------
// Kernel Q: query fp32 -> bf16 (same layout).
// ---------------------------------------------------------------------------
__global__ __launch_bounds__(256) void qconv_kernel(
    const float* __restrict__ q, short* __restrict__ qb) {
  int i = (blockIdx.x * 256 + threadIdx.x) * 8;
  float4 a = *(const float4*)&q[i];
  float4 b = *(const float4*)&q[i + 4];
  bf16x8 o;
  o[0] = f2bf(a.x); o[1] = f2bf(a.y); o[2] = f2bf(a.z); o[3] = f2bf(a.w);
  o[4] = f2bf(b.x); o[5] = f2bf(b.y); o[6] = f2bf(b.z); o[7] = f2bf(b.w);
  *(bf16x8*)&qb[i] = o;
}

// ---------------------------------------------------------------------------
// Kernel A: K/V projection + log_sigmoid(V), bf16 outputs in attention layouts:
//   keyb[b][h][l][d]  (row-major per head slice)
//   lsvt[b][h][d][l]  (transposed per head slice)
// l = nl*S + s (lane-major flatten of lanes).
// ---------------------------------------------------------------------------
__global__ __launch_bounds__(256) void proj_kernel(
    const float* __restrict__ lanes,
    const float* __restrict__ Wk, const float* __restrict__ bk,
    const float* __restrict__ Wv, const float* __restrict__ bv,
    short* __restrict__ keyb, short* __restrict__ lsvt) {
  __shared__ float in[32][64];
  int r0 = blockIdx.x * 32;
  int tid = threadIdx.x;
  for (int t = tid; t < 32 * 64 / 4; t += 256) {
    int rr = t >> 4;
    int i0 = (t & 15) * 4;
    int row = r0 + rr;
    int b = row >> 9, l = row & 511;
    int nl = l >> 5, s = l & 31;
    float4 v = *(const float4*)&lanes[((s * B_ + b) * NL_ + nl) * LF_ + i0];
    *(float4*)&in[rr][i0] = v;
  }
  __syncthreads();
  int f = tid;
  int b = r0 >> 9, l0 = r0 & 511;
  int h = f >> 5, d = f & 31;
  float accK[32], accV[32];
#pragma unroll
  for (int r = 0; r < 32; ++r) { accK[r] = 0.f; accV[r] = 0.f; }
  for (int i = 0; i < 64; ++i) {
    float wk = Wk[i * F_ + f];
    float wv = Wv[i * F_ + f];
#pragma unroll
    for (int r = 0; r < 32; ++r) {
      accK[r] = fmaf(in[r][i], wk, accK[r]);
      accV[r] = fmaf(in[r][i], wv, accV[r]);
    }
  }
  float bkf = bk[f], bvf = bv[f];
  // keyb: scalar bf16 stores (lanes 0-31 of a wave are contiguous in d)
#pragma unroll
  for (int r = 0; r < 32; ++r)
    keyb[((b * H_ + h) * L_ + l0 + r) * D_ + d] = f2bf(accK[r] + bkf);
  // lsvt: packed bf16x8 stores along l
#pragma unroll
  for (int c = 0; c < 4; ++c) {
    bf16x8 pk;
#pragma unroll
    for (int e = 0; e < 8; ++e) {
      float x = accV[c * 8 + e] + bvf;
      float ls = fminf(x, 0.f) - log1pf(__expf(-fabsf(x)));  // log_sigmoid
      pk[e] = f2bf(ls);
    }
    *(bf16x8*)&lsvt[((b * H_ + h) * D_ + d) * L_ + l0 + c * 8] = pk;
  }
}

// ---------------------------------------------------------------------------
// Kernel B: MFMA attention. One block per (b,h), 8 waves, 512 threads.
// K tile [512][40] bf16 + lsvT [32][520] bf16 staged once in LDS (1 barrier).
// Each wave handles 3 bands of 16 q-rows (band = wave + 8*bi; p=band>>1,
// vb=(band&1)*16). Per 128-l chunk: 8 score MFMAs -> mask -> exp(s-40) ->
// bf16 P via XOR-swizzled per-wave LDS buffer -> 8 PV MFMAs.
// Fixed-shift softmax: no row max needed (scores bounded), sum reduced at end.
// ---------------------------------------------------------------------------
__global__ __launch_bounds__(512, 2) void attn_kernel(
    const short* __restrict__ qb, const short* __restrict__ keyb,
    const short* __restrict__ lsvt,
    const unsigned int* __restrict__ maskr, const int* __restrict__ mi,
    float* __restrict__ out0) {
  __shared__ short Ks[512 * 40];       // 40960 B, rows padded to 40 (80 B)
  __shared__ short Vt[32 * 520];       // 33280 B, rows padded to 520 (1040 B)
  __shared__ short Pb[8][2048];        // 8 waves x [16][128] bf16, swizzled

  int bh = blockIdx.x;
  int b = bh >> 3, h = bh & 7;
  int tid = threadIdx.x;
  int w = tid >> 6, lane = tid & 63;
  int r = lane & 15, g = lane >> 4;

  // ---- stage K: thread t owns row l=t, 64B contiguous ----
  {
    int l = tid;
    const bf16x8* src = (const bf16x8*)&keyb[((b * H_ + h) * L_ + l) * D_];
#pragma unroll
    for (int c = 0; c < 4; ++c)
      *(bf16x8*)&Ks[l * 40 + c * 8] = src[c];
  }
  // ---- stage lsvT: thread t owns (d = t>>4, 32-l chunk) ----
  {
    int d = tid >> 4, lc = (tid & 15) * 32;
    const bf16x8* src = (const bf16x8*)&lsvt[((b * H_ + h) * D_ + d) * L_ + lc];
#pragma unroll
    for (int c = 0; c < 4; ++c)
      *(bf16x8*)&Vt[d * 520 + lc + c * 8] = src[c];
  }
  __syncthreads();

  // ---- per-band setup ----
  bf16x8 qf[3];
  int miv[3][4];
#pragma unroll
  for (int bi = 0; bi < 3; ++bi) {
    int band = w + bi * 8;
    int p = band >> 1, vb = (band & 1) << 4;
    qf[bi] = *(const bf16x8*)&qb[((p * B_ + b) * V_ + vb + r) * F_ + h * D_ + g * 8];
#pragma unroll
    for (int j = 0; j < 4; ++j)
      miv[bi][j] = mi[b * V_ + vb + g * 4 + j];
  }
  unsigned int mr = maskr[b * 16 + r];

  float rsum[3][4];
  f32x4 O[3][2];
#pragma unroll
  for (int bi = 0; bi < 3; ++bi) {
#pragma unroll
    for (int j = 0; j < 4; ++j) rsum[bi][j] = 0.f;
    O[bi][0] = (f32x4){0.f, 0.f, 0.f, 0.f};
    O[bi][1] = (f32x4){0.f, 0.f, 0.f, 0.f};
  }

  char* pw = (char*)&Pb[w][0];
  const f32x4 zero = {0.f, 0.f, 0.f, 0.f};

  for (int ch = 0; ch < 4; ++ch) {
    // K fragments for this chunk (shared by all 3 bands of this wave)
    bf16x8 Kf[8];
#pragma unroll
    for (int t = 0; t < 8; ++t)
      Kf[t] = *(const bf16x8*)((const char*)Ks + (((ch * 8 + t) * 16 + r) * 40 + g * 8) * 2);

#pragma unroll
    for (int bi = 0; bi < 3; ++bi) {
      // scores: lane holds S[v = g*4+j][l = (ch*8+t)*16 + r]
      f32x4 sc[8];
#pragma unroll
      for (int t = 0; t < 8; ++t)
        sc[t] = __builtin_amdgcn_mfma_f32_16x16x32_bf16(qf[bi], Kf[t], zero, 0, 0, 0);
      // mask + exp(s-40) + sum + bf16 + swizzled P write
#pragma unroll
      for (int t = 0; t < 8; ++t) {
        int bit = (mr >> (ch * 8 + t)) & 1;
#pragma unroll
        for (int j = 0; j < 4; ++j) {
          float s = (bit && miv[bi][j]) ? sc[t][j] : -1e9f;
          float pe = __expf(s - 40.f);
          rsum[bi][j] += pe;
          int row = g * 4 + j;
          *(short*)(pw + row * 256 + (((t * 16 + r) * 2) ^ ((row & 7) << 4))) = f2bf(pe);
        }
      }
      // PV: A = P[v=r][l], B = lsvT rows (cols d)
#pragma unroll
      for (int ks = 0; ks < 4; ++ks) {
        bf16x8 A = *(const bf16x8*)(pw + r * 256 + (((ks * 32 + g * 8) * 2) ^ ((r & 7) << 4)));
        bf16x8 B0 = *(const bf16x8*)((const char*)Vt + (r * 520 + ch * 128 + ks * 32 + g * 8) * 2);
        bf16x8 B1 = *(const bf16x8*)((const char*)Vt + ((16 + r) * 520 + ch * 128 + ks * 32 + g * 8) * 2);
        O[bi][0] = __builtin_amdgcn_mfma_f32_16x16x32_bf16(A, B0, O[bi][0], 0, 0, 0);
        O[bi][1] = __builtin_amdgcn_mfma_f32_16x16x32_bf16(A, B1, O[bi][1], 0, 0, 0);
      }
    }
  }

  // ---- normalize + exp + write out0 ----
#pragma unroll
  for (int bi = 0; bi < 3; ++bi) {
    int band = w + bi * 8;
    int p = band >> 1, vb = (band & 1) << 4;
#pragma unroll
    for (int j = 0; j < 4; ++j) {
      float rs = rsum[bi][j];
      rs += __shfl_xor(rs, 1);
      rs += __shfl_xor(rs, 2);
      rs += __shfl_xor(rs, 4);
      rs += __shfl_xor(rs, 8);
      float inv = rs > 0.f ? 1.f / rs : 0.f;
      int v = vb + g * 4 + j;
      float* op = &out0[((p * B_ + b) * V_ + v) * F_ + h * D_];
      op[r] = __expf(O[bi][0][j] * inv);
      op[16 + r] = __expf(O[bi][1][j] * inv);
    }
  }
}

// ---------------------------------------------------------------------------
// Kernel C: combine = out0 @ Wc + bc, 16 rows per block (fp32).
// ---------------------------------------------------------------------------
__global__ __launch_bounds__(256) void combine_kernel(
    const float* __restrict__ out0, const float* __restrict__ Wc,
    const float* __restrict__ bc, float* __restrict__ out) {
  __shared__ float rows[16][256];
  int r0 = blockIdx.x * 16;
  int tid = threadIdx.x;
  for (int t = tid; t < 16 * 256 / 4; t += 256) {
    int rr = t >> 6;
    int i0 = (t & 63) * 4;
    *(float4*)&rows[rr][i0] = *(const float4*)&out0[(r0 + rr) * F_ + i0];
  }
  __syncthreads();
  int f = tid;
  float acc[16];
#pragma unroll
  for (int r = 0; r < 16; ++r) acc[r] = 0.f;
  for (int i = 0; i < 256; ++i) {
    float wv = Wc[i * F_ + f];
#pragma unroll
    for (int r = 0; r < 16; ++r) acc[r] = fmaf(rows[r][i], wv, acc[r]);
  }
  float bcf = bc[f];
#pragma unroll
  for (int r = 0; r < 16; ++r) out[(r0 + r) * F_ + f] = acc[r] + bcf;
}

// ---------------------------------------------------------------------------
extern "C" void kernel_launch(void* const* d_in, const int* in_sizes, int n_in,
                              void* d_out, int out_size, void* d_ws, size_t ws_size,
                              hipStream_t stream) {
  const float* query = (const float*)d_in[0];
  const float* lanes = (const float*)d_in[1];
  const int* mask_input = (const int*)d_in[2];
  const int* mask_lanes = (const int*)d_in[3];
  const float* Wk = (const float*)d_in[4];
  const float* bk = (const float*)d_in[5];
  const float* Wv = (const float*)d_in[6];
  const float* bv = (const float*)d_in[7];
  const float* Wc = (const float*)d_in[8];
  const float* bc = (const float*)d_in[9];
  float* out = (float*)d_out;

  char* w = (char*)d_ws;
  short* qb = (short*)w;            w += 6291456;   // P*B*V*F bf16
  short* keyb = (short*)w;          w += 8388608;   // B*H*L*D bf16
  short* lsvt = (short*)w;          w += 8388608;   // B*H*D*L bf16
  float* out0 = (float*)w;          w += 12582912;  // P*B*V*F fp32
  unsigned int* maskr = (unsigned int*)w; w += 2048;
  int* mi = (int*)w;                w += 4096;

  masks_kernel<<<6, 256, 0, stream>>>(mask_input, mask_lanes, maskr, mi);
  qconv_kernel<<<P_ * B_ * V_ * F_ / (256 * 8), 256, 0, stream>>>(query, qb);
  proj_kernel<<<B_ * L_ / 32, 256, 0, stream>>>(lanes, Wk, bk, Wv, bv, keyb, lsvt);
  attn_kernel<<<B_ * H_, 512, 0, stream>>>(qb, keyb, lsvt, maskr, mi, out0);
  combine_kernel<<<P_ * B_ * V_ / 16, 256, 0, stream>>>(out0, Wc, bc, out);
}

// Round 4
// 88.116 us; speedup vs baseline: 6.2605x; 1.3023x over previous
//
#include <hip/hip_runtime.h>
#include <cstdint>

#define P_ 12
#define B_ 32
#define V_ 32
#define F_ 256
#define S_ 32
#define NL_ 16
#define LF_ 64
#define T_ 20
#define H_ 8
#define D_ 32
#define L_ 512

typedef short bf16x8 __attribute__((ext_vector_type(8)));
typedef short bf16x4 __attribute__((ext_vector_type(4)));
typedef float f32x4 __attribute__((ext_vector_type(4)));

static __device__ __forceinline__ short f2bf(float f) {
  uint32_t u = __builtin_bit_cast(uint32_t, f);
  uint32_t r = u + 0x7FFFu + ((u >> 16) & 1u);  // RNE
  return (short)(r >> 16);
}

// ---------------------------------------------------------------------------
// Kernel W: transpose weights to bf16 [out][in] layouts.
//  WkT[f][k] (256x64), WvT[f][k] (256x64), WcT[f][k] (256x256)
// ---------------------------------------------------------------------------
__global__ __launch_bounds__(256) void wconv_kernel(
    const float* __restrict__ Wk, const float* __restrict__ Wv,
    const float* __restrict__ Wc,
    short* __restrict__ WkT, short* __restrict__ WvT, short* __restrict__ WcT) {
  int t = blockIdx.x * 256 + threadIdx.x;
  if (t < 2048) {                 // WkT
    int f = t >> 3, k0 = (t & 7) * 8;
    bf16x8 o;
#pragma unroll
    for (int e = 0; e < 8; ++e) o[e] = f2bf(Wk[(k0 + e) * F_ + f]);
    *(bf16x8*)&WkT[f * LF_ + k0] = o;
  } else if (t < 4096) {          // WvT
    int i = t - 2048;
    int f = i >> 3, k0 = (i & 7) * 8;
    bf16x8 o;
#pragma unroll
    for (int e = 0; e < 8; ++e) o[e] = f2bf(Wv[(k0 + e) * F_ + f]);
    *(bf16x8*)&WvT[f * LF_ + k0] = o;
  } else if (t < 12288) {         // WcT
    int i = t - 4096;
    int f = i >> 5, k0 = (i & 31) * 8;
    bf16x8 o;
#pragma unroll
    for (int e = 0; e < 8; ++e) o[e] = f2bf(Wc[(k0 + e) * F_ + f]);
    *(bf16x8*)&WcT[f * F_ + k0] = o;
  }
}

// ---------------------------------------------------------------------------
// Kernel M: mask precompute (bools arrive as int32).
// ---------------------------------------------------------------------------
__global__ __launch_bounds__(256) void masks_kernel(
    const int* __restrict__ mask_input, const int* __restrict__ mask_lanes,
    unsigned int* __restrict__ maskr, int* __restrict__ mi) {
  int t = blockIdx.x * 256 + threadIdx.x;
  if (t < B_ * 16) {
    int b = t >> 4, r = t & 15;
    unsigned int bits = 0u;
    for (int lt = 0; lt < 32; ++lt)
      if (mask_lanes[(lt * B_ + b) * NL_ + r]) bits |= (1u << lt);
    maskr[t] = bits;
  } else if (t < B_ * 16 + B_ * V_) {
    int i = t - B_ * 16;
    int b = i >> 5, v = i & 31;
    int any = 0;
    for (int tt = 0; tt < T_; ++tt) any |= mask_input[(tt * B_ + b) * V_ + v];
    mi[i] = any ? 1 : 0;
  }
}

// ---------------------------------------------------------------------------
// Kernel Q: query fp32 -> bf16.
// ---------------------------------------------------------------------------
__global__ __launch_bounds__(256) void qconv_kernel(
    const float* __restrict__ q, short* __restrict__ qb) {
  int i = (blockIdx.x * 256 + threadIdx.x) * 8;
  float4 a = *(const float4*)&q[i];
  float4 b = *(const float4*)&q[i + 4];
  bf16x8 o;
  o[0] = f2bf(a.x); o[1] = f2bf(a.y); o[2] = f2bf(a.z); o[3] = f2bf(a.w);
  o[4] = f2bf(b.x); o[5] = f2bf(b.y); o[6] = f2bf(b.z); o[7] = f2bf(b.w);
  *(bf16x8*)&qb[i] = o;
}

// ---------------------------------------------------------------------------
// Kernel A (MFMA): K/V projection + log_sigmoid(V). No LDS, no barriers.
// 4 waves/block, wave owns 16 rows (l-tile). X frags direct from global
// (converted to bf16 in-register); weight frags from WkT/WvT.
//  K-GEMM swapped:  C[f][l] = mfma(A=WkT, B=X)  -> 8B stores keyb[l][d]
//  V-GEMM normal:   C[l][f] = mfma(A=X, B=WvT)  -> 8B stores lsvt[d][l]
// ---------------------------------------------------------------------------
__global__ __launch_bounds__(256) void proj_kernel(
    const float* __restrict__ lanes,
    const short* __restrict__ WkT, const short* __restrict__ WvT,
    const float* __restrict__ bk, const float* __restrict__ bv,
    short* __restrict__ keyb, short* __restrict__ lsvt) {
  int tid = threadIdx.x;
  int w = tid >> 6, lane = tid & 63;
  int r = lane & 15, g = lane >> 4;
  int R = blockIdx.x * 64 + w * 16;          // global row base of this wave
  int b = R >> 9;
  int lbase = R & 511;

  // X fragments: row (R+r), k = c*32 + g*8 .. +8  (fp32 -> bf16)
  int row = R + r;
  int l = row & 511;
  int nl = l >> 5, s = l & 31;
  const float* xrow = &lanes[((s * B_ + b) * NL_ + nl) * LF_];
  bf16x8 xf[2];
#pragma unroll
  for (int c = 0; c < 2; ++c) {
    float4 a = *(const float4*)&xrow[c * 32 + g * 8];
    float4 bq = *(const float4*)&xrow[c * 32 + g * 8 + 4];
    bf16x8 o;
    o[0] = f2bf(a.x); o[1] = f2bf(a.y); o[2] = f2bf(a.z); o[3] = f2bf(a.w);
    o[4] = f2bf(bq.x); o[5] = f2bf(bq.y); o[6] = f2bf(bq.z); o[7] = f2bf(bq.w);
    xf[c] = o;
  }

  const f32x4 zero = {0.f, 0.f, 0.f, 0.f};
#pragma unroll 4
  for (int ft = 0; ft < 16; ++ft) {
    int h = ft >> 1;
    int dlo = (ft & 1) << 4;
    // weight fragments: row ft*16 + r, k-chunk c
    bf16x8 wkf0 = *(const bf16x8*)&WkT[(ft * 16 + r) * LF_ + g * 8];
    bf16x8 wkf1 = *(const bf16x8*)&WkT[(ft * 16 + r) * LF_ + 32 + g * 8];
    bf16x8 wvf0 = *(const bf16x8*)&WvT[(ft * 16 + r) * LF_ + g * 8];
    bf16x8 wvf1 = *(const bf16x8*)&WvT[(ft * 16 + r) * LF_ + 32 + g * 8];

    f32x4 accK = __builtin_amdgcn_mfma_f32_16x16x32_bf16(wkf0, xf[0], zero, 0, 0, 0);
    accK = __builtin_amdgcn_mfma_f32_16x16x32_bf16(wkf1, xf[1], accK, 0, 0, 0);
    f32x4 accV = __builtin_amdgcn_mfma_f32_16x16x32_bf16(xf[0], wvf0, zero, 0, 0, 0);
    accV = __builtin_amdgcn_mfma_f32_16x16x32_bf16(xf[1], wvf1, accV, 0, 0, 0);

    // K epilogue: lane holds key[f = ft*16+g*4+reg][l = lbase + r]
    float4 bk4 = *(const float4*)&bk[ft * 16 + g * 4];
    bf16x4 ko;
    ko[0] = f2bf(accK[0] + bk4.x);
    ko[1] = f2bf(accK[1] + bk4.y);
    ko[2] = f2bf(accK[2] + bk4.z);
    ko[3] = f2bf(accK[3] + bk4.w);
    *(bf16x4*)&keyb[((b * H_ + h) * L_ + lbase + r) * D_ + dlo + g * 4] = ko;

    // V epilogue: lane holds val[l = lbase+g*4+reg][f = ft*16 + r]
    float bvf = bv[ft * 16 + r];
    int d = dlo + r;
    bf16x4 vo;
#pragma unroll
    for (int reg = 0; reg < 4; ++reg) {
      float x = accV[reg] + bvf;
      float ls = fminf(x, 0.f) - log1pf(__expf(-fabsf(x)));  // log_sigmoid
      vo[reg] = f2bf(ls);
    }
    *(bf16x4*)&lsvt[((b * H_ + h) * D_ + d) * L_ + lbase + g * 4] = vo;
  }
}

// ---------------------------------------------------------------------------
// Kernel B: MFMA attention (unchanged structure; now writes bf16 out0b).
// ---------------------------------------------------------------------------
__global__ __launch_bounds__(512, 2) void attn_kernel(
    const short* __restrict__ qb, const short* __restrict__ keyb,
    const short* __restrict__ lsvt,
    const unsigned int* __restrict__ maskr, const int* __restrict__ mi,
    short* __restrict__ out0b) {
  __shared__ short Ks[512 * 40];
  __shared__ short Vt[32 * 520];
  __shared__ short Pb[8][2048];

  int bh = blockIdx.x;
  int b = bh >> 3, h = bh & 7;
  int tid = threadIdx.x;
  int w = tid >> 6, lane = tid & 63;
  int r = lane & 15, g = lane >> 4;

  {
    int l = tid;
    const bf16x8* src = (const bf16x8*)&keyb[((b * H_ + h) * L_ + l) * D_];
#pragma unroll
    for (int c = 0; c < 4; ++c)
      *(bf16x8*)&Ks[l * 40 + c * 8] = src[c];
  }
  {
    int d = tid >> 4, lc = (tid & 15) * 32;
    const bf16x8* src = (const bf16x8*)&lsvt[((b * H_ + h) * D_ + d) * L_ + lc];
#pragma unroll
    for (int c = 0; c < 4; ++c)
      *(bf16x8*)&Vt[d * 520 + lc + c * 8] = src[c];
  }
  __syncthreads();

  bf16x8 qf[3];
  int miv[3][4];
#pragma unroll
  for (int bi = 0; bi < 3; ++bi) {
    int band = w + bi * 8;
    int p = band >> 1, vb = (band & 1) << 4;
    qf[bi] = *(const bf16x8*)&qb[((p * B_ + b) * V_ + vb + r) * F_ + h * D_ + g * 8];
#pragma unroll
    for (int j = 0; j < 4; ++j)
      miv[bi][j] = mi[b * V_ + vb + g * 4 + j];
  }
  unsigned int mr = maskr[b * 16 + r];

  float rsum[3][4];
  f32x4 O[3][2];
#pragma unroll
  for (int bi = 0; bi < 3; ++bi) {
#pragma unroll
    for (int j = 0; j < 4; ++j) rsum[bi][j] = 0.f;
    O[bi][0] = (f32x4){0.f, 0.f, 0.f, 0.f};
    O[bi][1] = (f32x4){0.f, 0.f, 0.f, 0.f};
  }

  char* pw = (char*)&Pb[w][0];
  const f32x4 zero = {0.f, 0.f, 0.f, 0.f};

  for (int ch = 0; ch < 4; ++ch) {
    bf16x8 Kf[8];
#pragma unroll
    for (int t = 0; t < 8; ++t)
      Kf[t] = *(const bf16x8*)((const char*)Ks + (((ch * 8 + t) * 16 + r) * 40 + g * 8) * 2);

#pragma unroll
    for (int bi = 0; bi < 3; ++bi) {
      f32x4 sc[8];
#pragma unroll
      for (int t = 0; t < 8; ++t)
        sc[t] = __builtin_amdgcn_mfma_f32_16x16x32_bf16(qf[bi], Kf[t], zero, 0, 0, 0);
#pragma unroll
      for (int t = 0; t < 8; ++t) {
        int bit = (mr >> (ch * 8 + t)) & 1;
#pragma unroll
        for (int j = 0; j < 4; ++j) {
          float s = (bit && miv[bi][j]) ? sc[t][j] : -1e9f;
          float pe = __expf(s - 40.f);
          rsum[bi][j] += pe;
          int row = g * 4 + j;
          *(short*)(pw + row * 256 + (((t * 16 + r) * 2) ^ ((row & 7) << 4))) = f2bf(pe);
        }
      }
#pragma unroll
      for (int ks = 0; ks < 4; ++ks) {
        bf16x8 A = *(const bf16x8*)(pw + r * 256 + (((ks * 32 + g * 8) * 2) ^ ((r & 7) << 4)));
        bf16x8 B0 = *(const bf16x8*)((const char*)Vt + (r * 520 + ch * 128 + ks * 32 + g * 8) * 2);
        bf16x8 B1 = *(const bf16x8*)((const char*)Vt + ((16 + r) * 520 + ch * 128 + ks * 32 + g * 8) * 2);
        O[bi][0] = __builtin_amdgcn_mfma_f32_16x16x32_bf16(A, B0, O[bi][0], 0, 0, 0);
        O[bi][1] = __builtin_amdgcn_mfma_f32_16x16x32_bf16(A, B1, O[bi][1], 0, 0, 0);
      }
    }
  }

#pragma unroll
  for (int bi = 0; bi < 3; ++bi) {
    int band = w + bi * 8;
    int p = band >> 1, vb = (band & 1) << 4;
#pragma unroll
    for (int j = 0; j < 4; ++j) {
      float rs = rsum[bi][j];
      rs += __shfl_xor(rs, 1);
      rs += __shfl_xor(rs, 2);
      rs += __shfl_xor(rs, 4);
      rs += __shfl_xor(rs, 8);
      float inv = rs > 0.f ? 1.f / rs : 0.f;
      int v = vb + g * 4 + j;
      short* op = &out0b[((p * B_ + b) * V_ + v) * F_ + h * D_];
      op[r] = f2bf(__expf(O[bi][0][j] * inv));
      op[16 + r] = f2bf(__expf(O[bi][1][j] * inv));
    }
  }
}

// ---------------------------------------------------------------------------
// Kernel C (MFMA): out = out0b @ Wc + bc. Swapped: C[f][l] = mfma(WcT, out0b)
// -> float4 output stores. 4 waves/block, wave owns 16 rows, K=256 (8 chunks).
// ---------------------------------------------------------------------------
__global__ __launch_bounds__(256) void combine_kernel(
    const short* __restrict__ out0b, const short* __restrict__ WcT,
    const float* __restrict__ bc, float* __restrict__ out) {
  int tid = threadIdx.x;
  int w = tid >> 6, lane = tid & 63;
  int r = lane & 15, g = lane >> 4;
  int R = blockIdx.x * 64 + w * 16;

  bf16x8 xf[8];
#pragma unroll
  for (int c = 0; c < 8; ++c)
    xf[c] = *(const bf16x8*)&out0b[(R + r) * F_ + c * 32 + g * 8];

  const f32x4 zero = {0.f, 0.f, 0.f, 0.f};
#pragma unroll 2
  for (int ft = 0; ft < 16; ++ft) {
    f32x4 acc = zero;
#pragma unroll
    for (int c = 0; c < 8; ++c) {
      bf16x8 wf = *(const bf16x8*)&WcT[(ft * 16 + r) * F_ + c * 32 + g * 8];
      acc = __builtin_amdgcn_mfma_f32_16x16x32_bf16(wf, xf[c], acc, 0, 0, 0);
    }
    // lane holds C[f = ft*16+g*4+reg][row = R + r]
    float4 bc4 = *(const float4*)&bc[ft * 16 + g * 4];
    float4 o;
    o.x = acc[0] + bc4.x;
    o.y = acc[1] + bc4.y;
    o.z = acc[2] + bc4.z;
    o.w = acc[3] + bc4.w;
    *(float4*)&out[(R + r) * F_ + ft * 16 + g * 4] = o;
  }
}

// ---------------------------------------------------------------------------
extern "C" void kernel_launch(void* const* d_in, const int* in_sizes, int n_in,
                              void* d_out, int out_size, void* d_ws, size_t ws_size,
                              hipStream_t stream) {
  const float* query = (const float*)d_in[0];
  const float* lanes = (const float*)d_in[1];
  const int* mask_input = (const int*)d_in[2];
  const int* mask_lanes = (const int*)d_in[3];
  const float* Wk = (const float*)d_in[4];
  const float* bk = (const float*)d_in[5];
  const float* Wv = (const float*)d_in[6];
  const float* bv = (const float*)d_in[7];
  const float* Wc = (const float*)d_in[8];
  const float* bc = (const float*)d_in[9];
  float* out = (float*)d_out;

  char* wp = (char*)d_ws;
  short* qb = (short*)wp;    wp += 6291456;   // P*B*V*F bf16
  short* keyb = (short*)wp;  wp += 8388608;   // B*H*L*D bf16
  short* lsvt = (short*)wp;  wp += 8388608;   // B*H*D*L bf16
  short* out0b = (short*)wp; wp += 6291456;   // P*B*V*F bf16
  short* WkT = (short*)wp;   wp += 32768;     // 256x64 bf16
  short* WvT = (short*)wp;   wp += 32768;
  short* WcT = (short*)wp;   wp += 131072;    // 256x256 bf16
  unsigned int* maskr = (unsigned int*)wp; wp += 2048;
  int* mi = (int*)wp;        wp += 4096;

  wconv_kernel<<<48, 256, 0, stream>>>(Wk, Wv, Wc, WkT, WvT, WcT);
  masks_kernel<<<6, 256, 0, stream>>>(mask_input, mask_lanes, maskr, mi);
  qconv_kernel<<<P_ * B_ * V_ * F_ / (256 * 8), 256, 0, stream>>>(query, qb);
  proj_kernel<<<B_ * L_ / 64, 256, 0, stream>>>(lanes, WkT, WvT, bk, bv, keyb, lsvt);
  attn_kernel<<<B_ * H_, 512, 0, stream>>>(qb, keyb, lsvt, maskr, mi, out0b);
  combine_kernel<<<P_ * B_ * V_ / 64, 256, 0, stream>>>(out0b, WcT, bc, out);
}

// Round 5
// 63.271 us; speedup vs baseline: 8.7189x; 1.3927x over previous
//
#include <hip/hip_runtime.h>
#include <cstdint>

#define P_ 12
#define B_ 32
#define V_ 32
#define F_ 256
#define S_ 32
#define NL_ 16
#define LF_ 64
#define T_ 20
#define H_ 8
#define D_ 32
#define L_ 512

typedef short bf16x8 __attribute__((ext_vector_type(8)));
typedef short bf16x4 __attribute__((ext_vector_type(4)));
typedef float f32x4 __attribute__((ext_vector_type(4)));

static __device__ __forceinline__ short f2bf(float f) {
  uint32_t u = __builtin_bit_cast(uint32_t, f);
  uint32_t r = u + 0x7FFFu + ((u >> 16) & 1u);  // RNE
  return (short)(r >> 16);
}

// ---------------------------------------------------------------------------
// Kernel P: prep = weight transpose/convert + mask precompute, one launch.
//  WkT[f][k] (256x64), WvT[f][k] (256x64), WcT[f][k] (256x256) bf16
//  maskr[b*16+r] bit lt = mask_lanes[lt,b,r];  mi[b*32+v] = any_t mask_input
// ---------------------------------------------------------------------------
__global__ __launch_bounds__(256) void prep_kernel(
    const float* __restrict__ Wk, const float* __restrict__ Wv,
    const float* __restrict__ Wc,
    const int* __restrict__ mask_input, const int* __restrict__ mask_lanes,
    short* __restrict__ WkT, short* __restrict__ WvT, short* __restrict__ WcT,
    unsigned int* __restrict__ maskr, int* __restrict__ mi) {
  int t = blockIdx.x * 256 + threadIdx.x;
  if (t < 2048) {                 // WkT
    int f = t >> 3, k0 = (t & 7) * 8;
    bf16x8 o;
#pragma unroll
    for (int e = 0; e < 8; ++e) o[e] = f2bf(Wk[(k0 + e) * F_ + f]);
    *(bf16x8*)&WkT[f * LF_ + k0] = o;
  } else if (t < 4096) {          // WvT
    int i = t - 2048;
    int f = i >> 3, k0 = (i & 7) * 8;
    bf16x8 o;
#pragma unroll
    for (int e = 0; e < 8; ++e) o[e] = f2bf(Wv[(k0 + e) * F_ + f]);
    *(bf16x8*)&WvT[f * LF_ + k0] = o;
  } else if (t < 12288) {         // WcT
    int i = t - 4096;
    int f = i >> 5, k0 = (i & 31) * 8;
    bf16x8 o;
#pragma unroll
    for (int e = 0; e < 8; ++e) o[e] = f2bf(Wc[(k0 + e) * F_ + f]);
    *(bf16x8*)&WcT[f * F_ + k0] = o;
  } else if (t < 12800) {         // maskr
    int i = t - 12288;
    int b = i >> 4, r = i & 15;
    unsigned int bits = 0u;
    for (int lt = 0; lt < 32; ++lt)
      if (mask_lanes[(lt * B_ + b) * NL_ + r]) bits |= (1u << lt);
    maskr[i] = bits;
  } else if (t < 13824) {         // mi
    int i = t - 12800;
    int b = i >> 5, v = i & 31;
    int any = 0;
    for (int tt = 0; tt < T_; ++tt) any |= mask_input[(tt * B_ + b) * V_ + v];
    mi[i] = any ? 1 : 0;
  }
}

// ---------------------------------------------------------------------------
// Kernel B: FUSED proj + attention. One block per (b,h), 8 waves.
// Stage phase: wave w computes K/V projections for l in [w*64,(w+1)*64)
// via MFMA directly into LDS tiles:
//   K swapped  C[d][l] = mfma(WkT_frag, X_frag) -> bf16x4 along d into Ks[l][d]
//   V normal   C[l][d] = mfma(X_frag, WvT_frag) -> bf16x4 along l into Vt[d][l]
// X frags loaded fp32 from lanes, converted in-register. One barrier.
// Attention phase: identical to round-4 proven structure; Q loaded fp32 and
// converted in-register (qconv eliminated).
// ---------------------------------------------------------------------------
__global__ __launch_bounds__(512, 2) void attn_kernel(
    const float* __restrict__ query, const float* __restrict__ lanes,
    const short* __restrict__ WkT, const short* __restrict__ WvT,
    const float* __restrict__ bk, const float* __restrict__ bv,
    const unsigned int* __restrict__ maskr, const int* __restrict__ mi,
    short* __restrict__ out0b) {
  __shared__ short Ks[512 * 40];       // rows padded to 40 shorts (80 B)
  __shared__ short Vt[32 * 520];       // rows padded to 520 shorts (1040 B)
  __shared__ short Pb[8][2048];        // per-wave P transpose buffer

  int bh = blockIdx.x;
  int b = bh >> 3, h = bh & 7;
  int tid = threadIdx.x;
  int w = tid >> 6, lane = tid & 63;
  int r = lane & 15, g = lane >> 4;
  const f32x4 zero = {0.f, 0.f, 0.f, 0.f};

  // ================= stage phase: K/V projection via MFMA =================
  {
    // weight fragments for head h (reused across 4 l-tiles)
    bf16x8 wk[2][2], wv[2][2];
#pragma unroll
    for (int dt = 0; dt < 2; ++dt)
#pragma unroll
      for (int c = 0; c < 2; ++c) {
        int f = h * 32 + dt * 16 + r;
        wk[dt][c] = *(const bf16x8*)&WkT[f * LF_ + c * 32 + g * 8];
        wv[dt][c] = *(const bf16x8*)&WvT[f * LF_ + c * 32 + g * 8];
      }
    float4 bk4[2];
    float bvf[2];
#pragma unroll
    for (int dt = 0; dt < 2; ++dt) {
      bk4[dt] = *(const float4*)&bk[h * 32 + dt * 16 + g * 4];
      bvf[dt] = bv[h * 32 + dt * 16 + r];
    }

#pragma unroll
    for (int lt = 0; lt < 4; ++lt) {
      int l0 = w * 64 + lt * 16;
      // X fragment: row l0+r, k = c*32 + g*8 (fp32 -> bf16)
      int l = l0 + r;
      int nl = l >> 5, s = l & 31;
      const float* xrow = &lanes[((s * B_ + b) * NL_ + nl) * LF_];
      bf16x8 xf[2];
#pragma unroll
      for (int c = 0; c < 2; ++c) {
        float4 a = *(const float4*)&xrow[c * 32 + g * 8];
        float4 q = *(const float4*)&xrow[c * 32 + g * 8 + 4];
        bf16x8 o;
        o[0] = f2bf(a.x); o[1] = f2bf(a.y); o[2] = f2bf(a.z); o[3] = f2bf(a.w);
        o[4] = f2bf(q.x); o[5] = f2bf(q.y); o[6] = f2bf(q.z); o[7] = f2bf(q.w);
        xf[c] = o;
      }
#pragma unroll
      for (int dt = 0; dt < 2; ++dt) {
        // K: C[d][l], lane holds d = dt*16+g*4+reg at l = l0+r
        f32x4 aK = __builtin_amdgcn_mfma_f32_16x16x32_bf16(wk[dt][0], xf[0], zero, 0, 0, 0);
        aK = __builtin_amdgcn_mfma_f32_16x16x32_bf16(wk[dt][1], xf[1], aK, 0, 0, 0);
        bf16x4 ko;
        ko[0] = f2bf(aK[0] + bk4[dt].x);
        ko[1] = f2bf(aK[1] + bk4[dt].y);
        ko[2] = f2bf(aK[2] + bk4[dt].z);
        ko[3] = f2bf(aK[3] + bk4[dt].w);
        *(bf16x4*)&Ks[(l0 + r) * 40 + dt * 16 + g * 4] = ko;
        // V: C[l][d], lane holds l = l0+g*4+reg at d = dt*16+r
        f32x4 aV = __builtin_amdgcn_mfma_f32_16x16x32_bf16(xf[0], wv[dt][0], zero, 0, 0, 0);
        aV = __builtin_amdgcn_mfma_f32_16x16x32_bf16(xf[1], wv[dt][1], aV, 0, 0, 0);
        bf16x4 vo;
#pragma unroll
        for (int reg = 0; reg < 4; ++reg) {
          float x = aV[reg] + bvf[dt];
          float ls = fminf(x, 0.f) - log1pf(__expf(-fabsf(x)));  // log_sigmoid
          vo[reg] = f2bf(ls);
        }
        *(bf16x4*)&Vt[(dt * 16 + r) * 520 + l0 + g * 4] = vo;
      }
    }
  }

  // ================= attention phase =================
  bf16x8 qf[3];
  int miv[3][4];
#pragma unroll
  for (int bi = 0; bi < 3; ++bi) {
    int band = w + bi * 8;
    int p = band >> 1, vb = (band & 1) << 4;
    const float* qp = &query[((p * B_ + b) * V_ + vb + r) * F_ + h * D_ + g * 8];
    float4 a = *(const float4*)qp;
    float4 q = *(const float4*)(qp + 4);
    bf16x8 o;
    o[0] = f2bf(a.x); o[1] = f2bf(a.y); o[2] = f2bf(a.z); o[3] = f2bf(a.w);
    o[4] = f2bf(q.x); o[5] = f2bf(q.y); o[6] = f2bf(q.z); o[7] = f2bf(q.w);
    qf[bi] = o;
#pragma unroll
    for (int j = 0; j < 4; ++j)
      miv[bi][j] = mi[b * V_ + vb + g * 4 + j];
  }
  unsigned int mr = maskr[b * 16 + r];

  float rsum[3][4];
  f32x4 O[3][2];
#pragma unroll
  for (int bi = 0; bi < 3; ++bi) {
#pragma unroll
    for (int j = 0; j < 4; ++j) rsum[bi][j] = 0.f;
    O[bi][0] = zero;
    O[bi][1] = zero;
  }

  __syncthreads();

  char* pw = (char*)&Pb[w][0];

  for (int ch = 0; ch < 4; ++ch) {
    bf16x8 Kf[8];
#pragma unroll
    for (int t = 0; t < 8; ++t)
      Kf[t] = *(const bf16x8*)((const char*)Ks + (((ch * 8 + t) * 16 + r) * 40 + g * 8) * 2);

#pragma unroll
    for (int bi = 0; bi < 3; ++bi) {
      f32x4 sc[8];
#pragma unroll
      for (int t = 0; t < 8; ++t)
        sc[t] = __builtin_amdgcn_mfma_f32_16x16x32_bf16(qf[bi], Kf[t], zero, 0, 0, 0);
#pragma unroll
      for (int t = 0; t < 8; ++t) {
        int bit = (mr >> (ch * 8 + t)) & 1;
#pragma unroll
        for (int j = 0; j < 4; ++j) {
          float s = (bit && miv[bi][j]) ? sc[t][j] : -1e9f;
          float pe = __expf(s - 40.f);
          rsum[bi][j] += pe;
          int row = g * 4 + j;
          *(short*)(pw + row * 256 + (((t * 16 + r) * 2) ^ ((row & 7) << 4))) = f2bf(pe);
        }
      }
#pragma unroll
      for (int ks = 0; ks < 4; ++ks) {
        bf16x8 A = *(const bf16x8*)(pw + r * 256 + (((ks * 32 + g * 8) * 2) ^ ((r & 7) << 4)));
        bf16x8 B0 = *(const bf16x8*)((const char*)Vt + (r * 520 + ch * 128 + ks * 32 + g * 8) * 2);
        bf16x8 B1 = *(const bf16x8*)((const char*)Vt + ((16 + r) * 520 + ch * 128 + ks * 32 + g * 8) * 2);
        O[bi][0] = __builtin_amdgcn_mfma_f32_16x16x32_bf16(A, B0, O[bi][0], 0, 0, 0);
        O[bi][1] = __builtin_amdgcn_mfma_f32_16x16x32_bf16(A, B1, O[bi][1], 0, 0, 0);
      }
    }
  }

#pragma unroll
  for (int bi = 0; bi < 3; ++bi) {
    int band = w + bi * 8;
    int p = band >> 1, vb = (band & 1) << 4;
#pragma unroll
    for (int j = 0; j < 4; ++j) {
      float rs = rsum[bi][j];
      rs += __shfl_xor(rs, 1);
      rs += __shfl_xor(rs, 2);
      rs += __shfl_xor(rs, 4);
      rs += __shfl_xor(rs, 8);
      float inv = rs > 0.f ? 1.f / rs : 0.f;
      int v = vb + g * 4 + j;
      short* op = &out0b[((p * B_ + b) * V_ + v) * F_ + h * D_];
      op[r] = f2bf(__expf(O[bi][0][j] * inv));
      op[16 + r] = f2bf(__expf(O[bi][1][j] * inv));
    }
  }
}

// ---------------------------------------------------------------------------
// Kernel C (MFMA): out = out0b @ Wc + bc. Swapped: C[f][l] = mfma(WcT, out0b)
// ---------------------------------------------------------------------------
__global__ __launch_bounds__(256) void combine_kernel(
    const short* __restrict__ out0b, const short* __restrict__ WcT,
    const float* __restrict__ bc, float* __restrict__ out) {
  int tid = threadIdx.x;
  int w = tid >> 6, lane = tid & 63;
  int r = lane & 15, g = lane >> 4;
  int R = blockIdx.x * 64 + w * 16;

  bf16x8 xf[8];
#pragma unroll
  for (int c = 0; c < 8; ++c)
    xf[c] = *(const bf16x8*)&out0b[(R + r) * F_ + c * 32 + g * 8];

  const f32x4 zero = {0.f, 0.f, 0.f, 0.f};
#pragma unroll 2
  for (int ft = 0; ft < 16; ++ft) {
    f32x4 acc = zero;
#pragma unroll
    for (int c = 0; c < 8; ++c) {
      bf16x8 wf = *(const bf16x8*)&WcT[(ft * 16 + r) * F_ + c * 32 + g * 8];
      acc = __builtin_amdgcn_mfma_f32_16x16x32_bf16(wf, xf[c], acc, 0, 0, 0);
    }
    float4 bc4 = *(const float4*)&bc[ft * 16 + g * 4];
    float4 o;
    o.x = acc[0] + bc4.x;
    o.y = acc[1] + bc4.y;
    o.z = acc[2] + bc4.z;
    o.w = acc[3] + bc4.w;
    *(float4*)&out[(R + r) * F_ + ft * 16 + g * 4] = o;
  }
}

// ---------------------------------------------------------------------------
extern "C" void kernel_launch(void* const* d_in, const int* in_sizes, int n_in,
                              void* d_out, int out_size, void* d_ws, size_t ws_size,
                              hipStream_t stream) {
  const float* query = (const float*)d_in[0];
  const float* lanes = (const float*)d_in[1];
  const int* mask_input = (const int*)d_in[2];
  const int* mask_lanes = (const int*)d_in[3];
  const float* Wk = (const float*)d_in[4];
  const float* bk = (const float*)d_in[5];
  const float* Wv = (const float*)d_in[6];
  const float* bv = (const float*)d_in[7];
  const float* Wc = (const float*)d_in[8];
  const float* bc = (const float*)d_in[9];
  float* out = (float*)d_out;

  char* wp = (char*)d_ws;
  short* out0b = (short*)wp; wp += 6291456;   // P*B*V*F bf16
  short* WkT = (short*)wp;   wp += 32768;     // 256x64 bf16
  short* WvT = (short*)wp;   wp += 32768;
  short* WcT = (short*)wp;   wp += 131072;    // 256x256 bf16
  unsigned int* maskr = (unsigned int*)wp; wp += 2048;
  int* mi = (int*)wp;        wp += 4096;

  prep_kernel<<<54, 256, 0, stream>>>(Wk, Wv, Wc, mask_input, mask_lanes,
                                      WkT, WvT, WcT, maskr, mi);
  attn_kernel<<<B_ * H_, 512, 0, stream>>>(query, lanes, WkT, WvT, bk, bv,
                                           maskr, mi, out0b);
  combine_kernel<<<P_ * B_ * V_ / 64, 256, 0, stream>>>(out0b, WcT, bc, out);
}

// Round 6
// 60.514 us; speedup vs baseline: 9.1162x; 1.0456x over previous
//
#include <hip/hip_runtime.h>
#include <cstdint>

#define P_ 12
#define B_ 32
#define V_ 32
#define F_ 256
#define S_ 32
#define NL_ 16
#define LF_ 64
#define T_ 20
#define H_ 8
#define D_ 32
#define L_ 512

typedef short bf16x8 __attribute__((ext_vector_type(8)));
typedef short bf16x4 __attribute__((ext_vector_type(4)));
typedef float f32x4 __attribute__((ext_vector_type(4)));

static __device__ __forceinline__ short f2bf(float f) {
  uint32_t u = __builtin_bit_cast(uint32_t, f);
  uint32_t r = u + 0x7FFFu + ((u >> 16) & 1u);  // RNE
  return (short)(r >> 16);
}

// packed f32x2 -> bf16x2 (RNE), 1 VALU op
static __device__ __forceinline__ uint32_t cvtpk(float lo, float hi) {
  uint32_t r;
  asm("v_cvt_pk_bf16_f32 %0, %1, %2" : "=v"(r) : "v"(lo), "v"(hi));
  return r;
}
static __device__ __forceinline__ bf16x8 pack8(uint32_t d0, uint32_t d1,
                                               uint32_t d2, uint32_t d3) {
  uint4 u = {d0, d1, d2, d3};
  return __builtin_bit_cast(bf16x8, u);
}
static __device__ __forceinline__ bf16x4 pack4(uint32_t d0, uint32_t d1) {
  uint2 u = {d0, d1};
  return __builtin_bit_cast(bf16x4, u);
}

// ---------------------------------------------------------------------------
// Kernel P: prep = weight transpose/convert + mask precompute.
// ---------------------------------------------------------------------------
__global__ __launch_bounds__(256) void prep_kernel(
    const float* __restrict__ Wk, const float* __restrict__ Wv,
    const float* __restrict__ Wc,
    const int* __restrict__ mask_input, const int* __restrict__ mask_lanes,
    short* __restrict__ WkT, short* __restrict__ WvT, short* __restrict__ WcT,
    unsigned int* __restrict__ maskr, int* __restrict__ mi) {
  int t = blockIdx.x * 256 + threadIdx.x;
  if (t < 2048) {                 // WkT
    int f = t >> 3, k0 = (t & 7) * 8;
    bf16x8 o;
#pragma unroll
    for (int e = 0; e < 8; ++e) o[e] = f2bf(Wk[(k0 + e) * F_ + f]);
    *(bf16x8*)&WkT[f * LF_ + k0] = o;
  } else if (t < 4096) {          // WvT
    int i = t - 2048;
    int f = i >> 3, k0 = (i & 7) * 8;
    bf16x8 o;
#pragma unroll
    for (int e = 0; e < 8; ++e) o[e] = f2bf(Wv[(k0 + e) * F_ + f]);
    *(bf16x8*)&WvT[f * LF_ + k0] = o;
  } else if (t < 12288) {         // WcT
    int i = t - 4096;
    int f = i >> 5, k0 = (i & 31) * 8;
    bf16x8 o;
#pragma unroll
    for (int e = 0; e < 8; ++e) o[e] = f2bf(Wc[(k0 + e) * F_ + f]);
    *(bf16x8*)&WcT[f * F_ + k0] = o;
  } else if (t < 12800) {         // maskr: word = l&15, bit = l>>4
    int i = t - 12288;
    int b = i >> 4, r = i & 15;
    unsigned int bits = 0u;
    for (int lt = 0; lt < 32; ++lt)
      if (mask_lanes[(lt * B_ + b) * NL_ + r]) bits |= (1u << lt);
    maskr[i] = bits;
  } else if (t < 13824) {         // mi
    int i = t - 12800;
    int b = i >> 5, v = i & 31;
    int any = 0;
    for (int tt = 0; tt < T_; ++tt) any |= mask_input[(tt * B_ + b) * V_ + v];
    mi[i] = any ? 1 : 0;
  }
}

// ---------------------------------------------------------------------------
// Kernel B: FUSED proj + attention, swapped-QK / permuted-K design.
// One block per (b,h), 8 waves, XCD-swizzled blockIdx.
//
// Stage: K rows stored at sigma(l) = swap bits[4]<->[3:2] of (l&31):
//   sigma(l) = (l&~31) | ((l>>2)&1)<<4 | ((l>>3)&3)<<2 | (l&3)
// Scores (swapped): sc[t] = mfma(Kf[t], qf) -> lane (r,g) holds
//   S[true l = ch*128 + 32*(t>>1) + 8g + 4*(t&1) + j][v = r]
// => lane's 32 exp'd values per ch ARE the PV A-fragment for v=r:
//   pa[ks][e=4c+j] = P[r][32ks+8g+e] -- pure in-register cvt_pk, no LDS.
// PV: O = mfma(pa, Vt-frag) -> O[v=g*4+j][d=r], same epilogue as before.
// ---------------------------------------------------------------------------
__global__ __launch_bounds__(512, 2) void attn_kernel(
    const float* __restrict__ query, const float* __restrict__ lanes,
    const short* __restrict__ WkT, const short* __restrict__ WvT,
    const float* __restrict__ bk, const float* __restrict__ bv,
    const unsigned int* __restrict__ maskr, const int* __restrict__ mi,
    short* __restrict__ out0b) {
  __shared__ short Ks[512 * 40];       // rows (permuted) padded to 40 shorts
  __shared__ short Vt[32 * 520];       // d-rows padded to 520 shorts

  // XCD swizzle: each XCD gets 4 consecutive b (all 8 h) -> X/query L2 reuse
  int i0 = blockIdx.x;
  int xcd = i0 & 7, sl0 = i0 >> 3;
  int b = xcd * 4 + (sl0 >> 3), h = sl0 & 7;

  int tid = threadIdx.x;
  int w = tid >> 6, lane = tid & 63;
  int r = lane & 15, g = lane >> 4;
  const f32x4 zero = {0.f, 0.f, 0.f, 0.f};

  // ================= stage phase: K/V projection via MFMA =================
  {
    bf16x8 wk[2][2], wv[2][2];
#pragma unroll
    for (int dt = 0; dt < 2; ++dt)
#pragma unroll
      for (int c = 0; c < 2; ++c) {
        int f = h * 32 + dt * 16 + r;
        wk[dt][c] = *(const bf16x8*)&WkT[f * LF_ + c * 32 + g * 8];
        wv[dt][c] = *(const bf16x8*)&WvT[f * LF_ + c * 32 + g * 8];
      }
    float4 bk4[2];
    float bvf[2];
#pragma unroll
    for (int dt = 0; dt < 2; ++dt) {
      bk4[dt] = *(const float4*)&bk[h * 32 + dt * 16 + g * 4];
      bvf[dt] = bv[h * 32 + dt * 16 + r];
    }

#pragma unroll
    for (int lt = 0; lt < 4; ++lt) {
      int l0 = w * 64 + lt * 16;
      int l = l0 + r;
      int nl = l >> 5, s = l & 31;
      const float* xrow = &lanes[((s * B_ + b) * NL_ + nl) * LF_];
      bf16x8 xf[2];
#pragma unroll
      for (int c = 0; c < 2; ++c) {
        float4 a = *(const float4*)&xrow[c * 32 + g * 8];
        float4 q = *(const float4*)&xrow[c * 32 + g * 8 + 4];
        xf[c] = pack8(cvtpk(a.x, a.y), cvtpk(a.z, a.w),
                      cvtpk(q.x, q.y), cvtpk(q.z, q.w));
      }
      // permuted K row index
      int sl = (l & ~31) | (((l >> 2) & 1) << 4) | (((l >> 3) & 3) << 2) | (l & 3);
#pragma unroll
      for (int dt = 0; dt < 2; ++dt) {
        f32x4 aK = __builtin_amdgcn_mfma_f32_16x16x32_bf16(wk[dt][0], xf[0], zero, 0, 0, 0);
        aK = __builtin_amdgcn_mfma_f32_16x16x32_bf16(wk[dt][1], xf[1], aK, 0, 0, 0);
        *(bf16x4*)&Ks[sl * 40 + dt * 16 + g * 4] =
            pack4(cvtpk(aK[0] + bk4[dt].x, aK[1] + bk4[dt].y),
                  cvtpk(aK[2] + bk4[dt].z, aK[3] + bk4[dt].w));
        f32x4 aV = __builtin_amdgcn_mfma_f32_16x16x32_bf16(xf[0], wv[dt][0], zero, 0, 0, 0);
        aV = __builtin_amdgcn_mfma_f32_16x16x32_bf16(xf[1], wv[dt][1], aV, 0, 0, 0);
        float ls[4];
#pragma unroll
        for (int reg = 0; reg < 4; ++reg) {
          float x = aV[reg] + bvf[dt];
          ls[reg] = fminf(x, 0.f) - log1pf(__expf(-fabsf(x)));  // log_sigmoid
        }
        *(bf16x4*)&Vt[(dt * 16 + r) * 520 + l0 + g * 4] =
            pack4(cvtpk(ls[0], ls[1]), cvtpk(ls[2], ls[3]));
      }
    }
  }

  // ================= per-band setup =================
  bf16x8 qf[3];
  float mivf[3];
#pragma unroll
  for (int bi = 0; bi < 3; ++bi) {
    int band = w + bi * 8;
    int p = band >> 1, vb = (band & 1) << 4;
    const float* qp = &query[((p * B_ + b) * V_ + vb + r) * F_ + h * D_ + g * 8];
    float4 a = *(const float4*)qp;
    float4 q = *(const float4*)(qp + 4);
    qf[bi] = pack8(cvtpk(a.x, a.y), cvtpk(a.z, a.w),
                   cvtpk(q.x, q.y), cvtpk(q.z, q.w));
    mivf[bi] = mi[b * V_ + vb + r] ? 1.f : 0.f;   // v = r (swapped layout)
  }
  // mask words for this lane's l-subset: word idx = 8*(g&1) + (4c+j)
  unsigned int mw[8];
#pragma unroll
  for (int q8 = 0; q8 < 8; ++q8) mw[q8] = maskr[b * 16 + ((g & 1) << 3) + q8];
  int ghalf = g >> 1;

  float rsum[3] = {0.f, 0.f, 0.f};
  f32x4 O[3][2];
#pragma unroll
  for (int bi = 0; bi < 3; ++bi) { O[bi][0] = zero; O[bi][1] = zero; }

  __syncthreads();

  // ================= attention main loop =================
  for (int ch = 0; ch < 4; ++ch) {
    bf16x8 Kf[8];
#pragma unroll
    for (int t = 0; t < 8; ++t)
      Kf[t] = *(const bf16x8*)&Ks[((ch * 8 + t) * 16 + r) * 40 + g * 8];

    bf16x8 vbuf[4][2];   // bi-invariant V fragments
#pragma unroll
    for (int ks = 0; ks < 4; ++ks) {
      vbuf[ks][0] = *(const bf16x8*)&Vt[r * 520 + ch * 128 + ks * 32 + g * 8];
      vbuf[ks][1] = *(const bf16x8*)&Vt[(16 + r) * 520 + ch * 128 + ks * 32 + g * 8];
    }

    // mask bias, shared across the 3 bands:
    // true l = ch*128 + 32*(t>>1) + 8g + 4*(t&1) + j -> bit = ch*8 + 2*(t>>1) + (g>>1)
    float fb[8][4];
#pragma unroll
    for (int t = 0; t < 8; ++t) {
      int bitidx = ch * 8 + 2 * (t >> 1) + ghalf;
#pragma unroll
      for (int j = 0; j < 4; ++j)
        fb[t][j] = ((mw[4 * (t & 1) + j] >> bitidx) & 1u) ? -40.f : -1e9f;
    }

#pragma unroll
    for (int bi = 0; bi < 3; ++bi) {
      f32x4 sc[8];
#pragma unroll
      for (int t = 0; t < 8; ++t)
        sc[t] = __builtin_amdgcn_mfma_f32_16x16x32_bf16(Kf[t], qf[bi], zero, 0, 0, 0);
      float pp[8][4];
#pragma unroll
      for (int t = 0; t < 8; ++t)
#pragma unroll
        for (int j = 0; j < 4; ++j) {
          float p = __expf(sc[t][j] + fb[t][j]) * mivf[bi];
          pp[t][j] = p;
          rsum[bi] += p;
        }
#pragma unroll
      for (int ks = 0; ks < 4; ++ks) {
        bf16x8 pa = pack8(cvtpk(pp[2 * ks][0], pp[2 * ks][1]),
                          cvtpk(pp[2 * ks][2], pp[2 * ks][3]),
                          cvtpk(pp[2 * ks + 1][0], pp[2 * ks + 1][1]),
                          cvtpk(pp[2 * ks + 1][2], pp[2 * ks + 1][3]));
        O[bi][0] = __builtin_amdgcn_mfma_f32_16x16x32_bf16(pa, vbuf[ks][0], O[bi][0], 0, 0, 0);
        O[bi][1] = __builtin_amdgcn_mfma_f32_16x16x32_bf16(pa, vbuf[ks][1], O[bi][1], 0, 0, 0);
      }
    }
  }

  // ================= epilogue =================
#pragma unroll
  for (int bi = 0; bi < 3; ++bi) {
    int band = w + bi * 8;
    int p = band >> 1, vb = (band & 1) << 4;
    float rs = rsum[bi];
    rs += __shfl_xor(rs, 16);
    rs += __shfl_xor(rs, 32);
    float invv = rs > 0.f ? 1.f / rs : 0.f;   // valid for v = r, all g copies
#pragma unroll
    for (int j = 0; j < 4; ++j) {
      float inv = __shfl(invv, g * 4 + j);    // inv for v = g*4+j
      int v = vb + g * 4 + j;
      short* op = &out0b[((p * B_ + b) * V_ + v) * F_ + h * D_];
      op[r] = f2bf(__expf(O[bi][0][j] * inv));
      op[16 + r] = f2bf(__expf(O[bi][1][j] * inv));
    }
  }
}

// ---------------------------------------------------------------------------
// Kernel C (MFMA): out = out0b @ Wc + bc. Swapped: C[f][l] = mfma(WcT, out0b)
// ---------------------------------------------------------------------------
__global__ __launch_bounds__(256) void combine_kernel(
    const short* __restrict__ out0b, const short* __restrict__ WcT,
    const float* __restrict__ bc, float* __restrict__ out) {
  int tid = threadIdx.x;
  int w = tid >> 6, lane = tid & 63;
  int r = lane & 15, g = lane >> 4;
  int R = blockIdx.x * 64 + w * 16;

  bf16x8 xf[8];
#pragma unroll
  for (int c = 0; c < 8; ++c)
    xf[c] = *(const bf16x8*)&out0b[(R + r) * F_ + c * 32 + g * 8];

  const f32x4 zero = {0.f, 0.f, 0.f, 0.f};
#pragma unroll 2
  for (int ft = 0; ft < 16; ++ft) {
    f32x4 acc = zero;
#pragma unroll
    for (int c = 0; c < 8; ++c) {
      bf16x8 wf = *(const bf16x8*)&WcT[(ft * 16 + r) * F_ + c * 32 + g * 8];
      acc = __builtin_amdgcn_mfma_f32_16x16x32_bf16(wf, xf[c], acc, 0, 0, 0);
    }
    float4 bc4 = *(const float4*)&bc[ft * 16 + g * 4];
    float4 o;
    o.x = acc[0] + bc4.x;
    o.y = acc[1] + bc4.y;
    o.z = acc[2] + bc4.z;
    o.w = acc[3] + bc4.w;
    *(float4*)&out[(R + r) * F_ + ft * 16 + g * 4] = o;
  }
}

// ---------------------------------------------------------------------------
extern "C" void kernel_launch(void* const* d_in, const int* in_sizes, int n_in,
                              void* d_out, int out_size, void* d_ws, size_t ws_size,
                              hipStream_t stream) {
  const float* query = (const float*)d_in[0];
  const float* lanes = (const float*)d_in[1];
  const int* mask_input = (const int*)d_in[2];
  const int* mask_lanes = (const int*)d_in[3];
  const float* Wk = (const float*)d_in[4];
  const float* bk = (const float*)d_in[5];
  const float* Wv = (const float*)d_in[6];
  const float* bv = (const float*)d_in[7];
  const float* Wc = (const float*)d_in[8];
  const float* bc = (const float*)d_in[9];
  float* out = (float*)d_out;

  char* wp = (char*)d_ws;
  short* out0b = (short*)wp; wp += 6291456;   // P*B*V*F bf16
  short* WkT = (short*)wp;   wp += 32768;     // 256x64 bf16
  short* WvT = (short*)wp;   wp += 32768;
  short* WcT = (short*)wp;   wp += 131072;    // 256x256 bf16
  unsigned int* maskr = (unsigned int*)wp; wp += 2048;
  int* mi = (int*)wp;        wp += 4096;

  prep_kernel<<<54, 256, 0, stream>>>(Wk, Wv, Wc, mask_input, mask_lanes,
                                      WkT, WvT, WcT, maskr, mi);
  attn_kernel<<<B_ * H_, 512, 0, stream>>>(query, lanes, WkT, WvT, bk, bv,
                                           maskr, mi, out0b);
  combine_kernel<<<P_ * B_ * V_ / 64, 256, 0, stream>>>(out0b, WcT, bc, out);
}